// Round 2
// baseline (75.873 us; speedup 1.0000x reference)
//
#include <hip/hip_runtime.h>

// And_Convolution: out[n,w] = min_{j=0..15}( input[n, 4*w + j] * weight[j] )
// N=1024, L=8192, KERNEL=16, STRIDE=4 -> NWIN = 2045.
//
// Row-per-block LDS version: stage the 32 KB row once (coalesced float4,
// exactly one HBM pass, no redundant L1 traffic), then each thread computes
// 8 windows from LDS via 16B-stride reads (conflict-free ds_read_b128).

#define ROWLEN 8192
#define NCHUNK 2048   // ROWLEN / 4 float4 chunks
#define NWIN 2045     // (8192 - 16) / 4 + 1

__global__ __launch_bounds__(256) void and_conv_kernel(
    const float* __restrict__ inp,
    const float* __restrict__ wgt,
    float* __restrict__ out) {
    __shared__ float4 lds[NCHUNK];   // 32 KiB -> 5 blocks/CU LDS-wise

    const int t = threadIdx.x;
    const int n = blockIdx.x;

    const float4* row = (const float4*)(inp + (size_t)n * ROWLEN);

    // Stage row -> LDS: 8 coalesced float4 loads per thread (2048 chunks).
#pragma unroll
    for (int k = 0; k < 8; ++k) {
        const int g = k * 256 + t;
        lds[g] = row[g];
    }

    // Weights are wave-uniform -> scalar loads, overlapped with staging.
    const float4* wv = (const float4*)wgt;
    const float4 w0 = wv[0];
    const float4 w1 = wv[1];
    const float4 w2 = wv[2];
    const float4 w3 = wv[3];

    __syncthreads();

    float* outrow = out + (size_t)n * NWIN;

#pragma unroll
    for (int k = 0; k < 8; ++k) {
        const int w = k * 256 + t;                 // 0..2047
        const int wc = (w < NWIN) ? w : (NWIN - 1); // clamp: no OOB LDS read
        const float4 c0 = lds[wc];
        const float4 c1 = lds[wc + 1];
        const float4 c2 = lds[wc + 2];
        const float4 c3 = lds[wc + 3];

        const float m0 = fminf(fminf(c0.x * w0.x, c0.y * w0.y),
                               fminf(c0.z * w0.z, c0.w * w0.w));
        const float m1 = fminf(fminf(c1.x * w1.x, c1.y * w1.y),
                               fminf(c1.z * w1.z, c1.w * w1.w));
        const float m2 = fminf(fminf(c2.x * w2.x, c2.y * w2.y),
                               fminf(c2.z * w2.z, c2.w * w2.w));
        const float m3 = fminf(fminf(c3.x * w3.x, c3.y * w3.y),
                               fminf(c3.z * w3.z, c3.w * w3.w));

        if (w < NWIN) {
            outrow[w] = fminf(fminf(m0, m1), fminf(m2, m3));
        }
    }
}

extern "C" void kernel_launch(void* const* d_in, const int* in_sizes, int n_in,
                              void* d_out, int out_size, void* d_ws, size_t ws_size,
                              hipStream_t stream) {
    const float* inp = (const float*)d_in[0];
    const float* wgt = (const float*)d_in[1];
    float* out = (float*)d_out;

    const int N = in_sizes[0] / ROWLEN;  // 1024 rows, one block per row
    and_conv_kernel<<<dim3(N), dim3(256), 0, stream>>>(inp, wgt, out);
}